// Round 1
// baseline (53.079 us; speedup 1.0000x reference)
//
#include <hip/hip_runtime.h>
#include <hip/hip_bf16.h>

// LinearCombiner: the reference 3-layer MLP has NO activation, so the whole
// net is affine: out = M @ x + c with M = W3@W2@W1 (8x3072),
// c = W3@W2@b1 + W3@b2 + b3. And x[t,u] = [tmin[t]; tmax[t]; user[u]] is
// separable, so out[t,u,o] = P[t,o] + Q[u,o] + c[o].
//
// Pipeline (all deterministic, no atomics):
//  K1: partial GEMM  M2_partial = W3 @ W2 (K-split into 32 slices)
//  K2: reduce        M2 (8x3072)
//  K3: partial GEMM  M_partial  = M2 @ W1
//  K4: reduce        M (8x3072)
//  K5: bias fold     c = M2@b1 + W3@b2 + b3
//  K6: P[t,o] = sum_d M[o,d]*min(a,b)[t,d] + M[o,1024+d]*max(a,b)[t,d]
//  K7: Q[u,o] = sum_d M[o,2048+d]*user[u,d]
//  K8: out[t,u,o] = P[t,o] + Q[u,o] + c[o]

#define HIDN 3072
#define DIM 1024
#define NOUT 8
#define NSLICE 32
#define KPS 96            // 3072 / 32
#define TDIM 256
#define UDIM 128

// A: (8, HIDN) row-major; B: (HIDN, HIDN) row-major.
// partial[s][o][h] = sum_{k in slice s} A[o,k] * B[k,h]
__global__ void skinny_gemm_partial(const float* __restrict__ A,
                                    const float* __restrict__ B,
                                    float* __restrict__ partial) {
    const int h = blockIdx.x * 256 + threadIdx.x;   // [0, 3072)
    const int s = blockIdx.y;                       // [0, NSLICE)
    const int k0 = s * KPS;

    __shared__ float As[NOUT][KPS];
    for (int i = threadIdx.x; i < NOUT * KPS; i += 256) {
        int o = i / KPS, kk = i % KPS;
        As[o][kk] = A[o * HIDN + k0 + kk];
    }
    __syncthreads();

    float acc[NOUT];
#pragma unroll
    for (int o = 0; o < NOUT; ++o) acc[o] = 0.0f;

    const float* Bp = B + (size_t)k0 * HIDN + h;
#pragma unroll 4
    for (int kk = 0; kk < KPS; ++kk) {
        float b = Bp[(size_t)kk * HIDN];
#pragma unroll
        for (int o = 0; o < NOUT; ++o) acc[o] += As[o][kk] * b;
    }

#pragma unroll
    for (int o = 0; o < NOUT; ++o)
        partial[((size_t)s * NOUT + o) * HIDN + h] = acc[o];
}

__global__ void reduce_partials(const float* __restrict__ partial,
                                float* __restrict__ out) {
    const int i = blockIdx.x * 256 + threadIdx.x;   // [0, NOUT*HIDN)
    float acc = 0.0f;
#pragma unroll 4
    for (int s = 0; s < NSLICE; ++s)
        acc += partial[(size_t)s * (NOUT * HIDN) + i];
    out[i] = acc;
}

// c[o] = sum_k M2[o,k]*b1[k] + sum_k W3[o,k]*b2[k] + b3[o]
__global__ void bias_fold(const float* __restrict__ M2,
                          const float* __restrict__ W3,
                          const float* __restrict__ b1,
                          const float* __restrict__ b2,
                          const float* __restrict__ b3,
                          float* __restrict__ c) {
    const int o = blockIdx.x;
    float acc = 0.0f;
    for (int k = threadIdx.x; k < HIDN; k += 256)
        acc += M2[o * HIDN + k] * b1[k] + W3[o * HIDN + k] * b2[k];
    __shared__ float red[256];
    red[threadIdx.x] = acc;
    __syncthreads();
    for (int st = 128; st > 0; st >>= 1) {
        if (threadIdx.x < st) red[threadIdx.x] += red[threadIdx.x + st];
        __syncthreads();
    }
    if (threadIdx.x == 0) c[o] = red[0] + b3[o];
}

__device__ __forceinline__ void block_reduce8_store(float acc[NOUT],
                                                    float* __restrict__ dst) {
    const int tid = threadIdx.x;
    const int lane = tid & 63, w = tid >> 6;
#pragma unroll
    for (int o = 0; o < NOUT; ++o) {
#pragma unroll
        for (int off = 32; off > 0; off >>= 1)
            acc[o] += __shfl_down(acc[o], off, 64);
    }
    __shared__ float red[4][NOUT];
    if (lane == 0) {
#pragma unroll
        for (int o = 0; o < NOUT; ++o) red[w][o] = acc[o];
    }
    __syncthreads();
    if (tid < NOUT) {
        dst[tid] = red[0][tid] + red[1][tid] + red[2][tid] + red[3][tid];
    }
}

// P[t,o] = sum_{d<1024} M[o,d]*min(a,b) + M[o,1024+d]*max(a,b)
__global__ void text_project(const float* __restrict__ ta,
                             const float* __restrict__ tb,
                             const float* __restrict__ M,
                             float* __restrict__ P) {
    const int t = blockIdx.x;
    float acc[NOUT];
#pragma unroll
    for (int o = 0; o < NOUT; ++o) acc[o] = 0.0f;
    for (int d = threadIdx.x; d < DIM; d += 256) {
        float a = ta[t * DIM + d], b = tb[t * DIM + d];
        float mn = fminf(a, b), mx = fmaxf(a, b);
#pragma unroll
        for (int o = 0; o < NOUT; ++o)
            acc[o] += M[o * HIDN + d] * mn + M[o * HIDN + DIM + d] * mx;
    }
    block_reduce8_store(acc, P + t * NOUT);
}

// Q[u,o] = sum_{d<1024} M[o,2048+d]*user[u,d]
__global__ void user_project(const float* __restrict__ user,
                             const float* __restrict__ M,
                             float* __restrict__ Q) {
    const int u = blockIdx.x;
    float acc[NOUT];
#pragma unroll
    for (int o = 0; o < NOUT; ++o) acc[o] = 0.0f;
    for (int d = threadIdx.x; d < DIM; d += 256) {
        float x = user[u * DIM + d];
#pragma unroll
        for (int o = 0; o < NOUT; ++o)
            acc[o] += M[o * HIDN + 2 * DIM + d] * x;
    }
    block_reduce8_store(acc, Q + u * NOUT);
}

// out[t,u,o] = P[t,o] + Q[u,o] + c[o]
__global__ void combine_out(const float* __restrict__ P,
                            const float* __restrict__ Q,
                            const float* __restrict__ c,
                            float4* __restrict__ out) {
    const int idx = blockIdx.x * 256 + threadIdx.x;  // [0, T*U)
    const int t = idx >> 7, u = idx & (UDIM - 1);
    const float4* Pp = (const float4*)(P) + t * 2;
    const float4* Qp = (const float4*)(Q) + u * 2;
    const float4* Cp = (const float4*)(c);
    float4 p0 = Pp[0], p1 = Pp[1];
    float4 q0 = Qp[0], q1 = Qp[1];
    float4 c0 = Cp[0], c1 = Cp[1];
    float4 r0 = {p0.x + q0.x + c0.x, p0.y + q0.y + c0.y,
                 p0.z + q0.z + c0.z, p0.w + q0.w + c0.w};
    float4 r1 = {p1.x + q1.x + c1.x, p1.y + q1.y + c1.y,
                 p1.z + q1.z + c1.z, p1.w + q1.w + c1.w};
    out[idx * 2] = r0;
    out[idx * 2 + 1] = r1;
}

extern "C" void kernel_launch(void* const* d_in, const int* in_sizes, int n_in,
                              void* d_out, int out_size, void* d_ws, size_t ws_size,
                              hipStream_t stream) {
    const float* text_a = (const float*)d_in[0];
    const float* text_b = (const float*)d_in[1];
    const float* user   = (const float*)d_in[2];
    const float* W1 = (const float*)d_in[3];
    const float* b1 = (const float*)d_in[4];
    const float* W2 = (const float*)d_in[5];
    const float* b2 = (const float*)d_in[6];
    const float* W3 = (const float*)d_in[7];
    const float* b3 = (const float*)d_in[8];

    float* ws = (float*)d_ws;
    float* partial = ws;                                // NSLICE*NOUT*HIDN = 786432 floats
    float* M2 = partial + (size_t)NSLICE * NOUT * HIDN; // 24576 floats
    float* M  = M2 + NOUT * HIDN;                       // 24576 floats
    float* c  = M + NOUT * HIDN;                        // 8 floats
    float* P  = c + NOUT;                               // 2048 floats (16B-aligned)
    float* Q  = P + TDIM * NOUT;                        // 1024 floats

    // M2 = W3 @ W2
    skinny_gemm_partial<<<dim3(HIDN / 256, NSLICE), 256, 0, stream>>>(W3, W2, partial);
    reduce_partials<<<(NOUT * HIDN) / 256, 256, 0, stream>>>(partial, M2);
    // M = M2 @ W1
    skinny_gemm_partial<<<dim3(HIDN / 256, NSLICE), 256, 0, stream>>>(M2, W1, partial);
    reduce_partials<<<(NOUT * HIDN) / 256, 256, 0, stream>>>(partial, M);
    // c = M2@b1 + W3@b2 + b3
    bias_fold<<<NOUT, 256, 0, stream>>>(M2, W3, b1, b2, b3, c);
    // P, Q projections
    text_project<<<TDIM, 256, 0, stream>>>(text_a, text_b, M, P);
    user_project<<<UDIM, 256, 0, stream>>>(user, M, Q);
    // out = P + Q + c
    combine_out<<<(TDIM * UDIM) / 256, 256, 0, stream>>>(P, Q, c, (float4*)d_out);
}